// Round 7
// baseline (172.619 us; speedup 1.0000x reference)
//
#include <hip/hip_runtime.h>
#include <math.h>

#define NN 4096
#define IN_DIM 256
#define HEADS 4
#define OUT_DIM 64

typedef float f32x4 __attribute__((ext_vector_type(4)));

__device__ __forceinline__ float fexp(float x){ return __expf(x); }

// ---- K1: Wh = h@W fused with f_i/f_j/exp(f_j) tables ----
__global__ void k_gw(const float* __restrict__ h, const float* __restrict__ W,
                     const float* __restrict__ a,
                     float* __restrict__ Wh, float* __restrict__ fi, float* __restrict__ fjT,
                     float* __restrict__ E1j, float* __restrict__ E2j){
    __shared__ float4 hs4[8][64];         // 8 rows x 256 k  (8 KB)
    const int i0 = blockIdx.x * 8;
    const int t  = threadIdx.x;           // output column (256 cols)
    const int hh = t >> 6, d = t & 63;    // wave == head
    {
        const float4* h4 = (const float4*)h;
        hs4[t >> 6][t & 63]         = h4[(i0 + (t >> 6)) * 64 + (t & 63)];
        hs4[(t >> 6) + 4][t & 63]   = h4[(i0 + (t >> 6) + 4) * 64 + (t & 63)];
    }
    __syncthreads();
    float acc[8];
    #pragma unroll
    for (int r = 0; r < 8; ++r) acc[r] = 0.f;
    #pragma unroll 4
    for (int kq = 0; kq < 64; ++kq) {
        const int k = kq * 4;
        const float w0 = W[(k + 0) * 256 + t];
        const float w1 = W[(k + 1) * 256 + t];
        const float w2 = W[(k + 2) * 256 + t];
        const float w3 = W[(k + 3) * 256 + t];
        #pragma unroll
        for (int r = 0; r < 8; ++r) {
            const float4 hv = hs4[r][kq];     // wave-uniform -> LDS broadcast
            acc[r] = fmaf(hv.x, w0, acc[r]);
            acc[r] = fmaf(hv.y, w1, acc[r]);
            acc[r] = fmaf(hv.z, w2, acc[r]);
            acc[r] = fmaf(hv.w, w3, acc[r]);
        }
    }
    const float aD = a[hh * 128 + d];
    const float aS = a[hh * 128 + 64 + d];
    #pragma unroll
    for (int r = 0; r < 8; ++r) {
        Wh[(i0 + r) * 256 + t] = acc[r];
        float p1 = acc[r] * aD, p2 = acc[r] * aS;
        #pragma unroll
        for (int off = 32; off; off >>= 1) {
            p1 += __shfl_down(p1, off);
            p2 += __shfl_down(p2, off);
        }
        if (d == 0) {
            const int n = i0 + r;
            fi[n * 4 + hh]   = p1;
            fjT[hh * NN + n] = p2;
            E1j[n * 4 + hh]  = fexp(p2);
            E2j[n * 4 + hh]  = fexp(0.2f * p2);
        }
    }
}

// ---- K2: rank f_j per head + permute Wh into sorted order ----
__global__ void k_rp(const float* __restrict__ fjT, const float* __restrict__ Wh,
                     float* __restrict__ fs, float* __restrict__ Whp){
    const int j0 = blockIdx.x * 8;
    const int t = threadIdx.x;
    const int hh = t >> 6, d = t & 63;    // wave == head
    const int base = hh * NN;
    float v[8]; int cnt[8];
    #pragma unroll
    for (int r = 0; r < 8; ++r) { v[r] = fjT[base + j0 + r]; cnt[r] = 0; }
    #pragma unroll 4
    for (int m = 0; m < 64; ++m) {
        const int jp = d + m * 64;
        const float x = fjT[base + jp];
        #pragma unroll
        for (int r = 0; r < 8; ++r)
            cnt[r] += (x < v[r] || (x == v[r] && jp < (j0 + r))) ? 1 : 0;
    }
    #pragma unroll
    for (int r = 0; r < 8; ++r) {
        int c = cnt[r];
        #pragma unroll
        for (int off = 32; off; off >>= 1) c += __shfl_down(c, off);
        const int rank = __shfl(c, 0);
        if (d == 0) fs[base + rank] = v[r];
        Whp[(size_t)(base + rank) * 64 + d] = Wh[(j0 + r) * 256 + hh * 64 + d];
    }
}

// ---- K3: chunk totals only (no fine prefix materialization) ----
__global__ void k_chunks(const float* __restrict__ fs, const float* __restrict__ Whp,
                         float* __restrict__ cs1, float* __restrict__ cs2,
                         float* __restrict__ cz1, float* __restrict__ cz2){
    const int c = blockIdx.x;             // 64 chunks
    const int t = threadIdx.x;            // 4 waves = 4 heads
    const int hh = t >> 6, d = t & 63;
    const int base = hh * NN;
    const int q0 = c * 64;
    float a1 = 0.f, a2 = 0.f, z1 = 0.f, z2 = 0.f;
    #pragma unroll 4
    for (int q = q0; q < q0 + 64; ++q) {
        const float f  = fs[base + q];    // wave-uniform
        const float e1 = fexp(f), e2 = fexp(0.2f * f);
        const float wv = Whp[(size_t)(base + q) * 64 + d];
        a1 += e1 * wv; z1 += e1;
        a2 += e2 * wv; z2 += e2;
    }
    cs1[(hh * 64 + c) * 64 + d] = a1;
    cs2[(hh * 64 + c) * 64 + d] = a2;
    if (d == 0) { cz1[hh * 64 + c] = z1; cz2[hh * 64 + c] = z2; }
}

// ---- K4: chunk-level scans (one block per head) ----
__global__ void k_scan(const float* __restrict__ cs1, const float* __restrict__ cs2,
                       const float* __restrict__ cz1, const float* __restrict__ cz2,
                       float* __restrict__ S1, float* __restrict__ S2,
                       float* __restrict__ Z1, float* __restrict__ Z2){
    const int H = blockIdx.x;
    const int t = threadIdx.x;
    if (t < 64) {
        const int d = t; float acc = 0.f;
        S1[(H * 65 + 64) * 64 + d] = 0.f;
        #pragma unroll 8
        for (int c = 63; c >= 0; --c) { acc += cs1[(H * 64 + c) * 64 + d]; S1[(H * 65 + c) * 64 + d] = acc; }
    } else if (t < 128) {
        const int d = t - 64; float acc = 0.f;
        S2[(H * 65 + 0) * 64 + d] = 0.f;
        #pragma unroll 8
        for (int c = 0; c < 64; ++c) { acc += cs2[(H * 64 + c) * 64 + d]; S2[(H * 65 + c + 1) * 64 + d] = acc; }
    } else if (t == 128) {
        float acc = 0.f; Z1[H * 65 + 64] = 0.f;
        for (int c = 63; c >= 0; --c) { acc += cz1[H * 64 + c]; Z1[H * 65 + c] = acc; }
    } else if (t == 129) {
        float acc = 0.f; Z2[H * 65 + 0] = 0.f;
        for (int c = 0; c < 64; ++c) { acc += cz2[H * 64 + c]; Z2[H * 65 + c + 1] = acc; }
    }
}

// ---- K5: query — ballot search + within-chunk recompute ----
__global__ void k_q(const float* __restrict__ fi, const float* __restrict__ fs,
                    const float* __restrict__ Whp,
                    const float* __restrict__ S1, const float* __restrict__ S2,
                    const float* __restrict__ Z1, const float* __restrict__ Z2,
                    float* __restrict__ out, float* __restrict__ thrE,
                    float* __restrict__ A1, float* __restrict__ A2){
    const int i = blockIdx.x;
    const int t = threadIdx.x;
    const int hh = t >> 6, d = t & 63;    // wave == head
    const int base = hh * NN;
    const float s = fi[i * 4 + hh];
    const float thr = -s;
    const unsigned long long m1 = __ballot(fs[base + d * 64] < thr);
    const int k1 = __popcll(m1);
    int p = 0;
    if (k1 > 0) {
        const int cc = k1 - 1;
        const unsigned long long m2 = __ballot(fs[base + cc * 64 + d] < thr);
        p = cc * 64 + __popcll(m2);
    }
    const int c = min(p >> 6, 63);
    float a1 = 0.f, a2 = 0.f, z1 = 0.f, z2 = 0.f;
    const int q0 = c * 64;
    #pragma unroll 4
    for (int q = q0; q < q0 + 64; ++q) {
        const float f  = fs[base + q];                     // wave-uniform
        const float wv = Whp[(size_t)(base + q) * 64 + d]; // coalesced
        if (q >= p) { const float e = fexp(f);        a1 += e * wv; z1 += e; }
        else        { const float e = fexp(0.2f * f); a2 += e * wv; z2 += e; }
    }
    a1 += S1[(hh * 65 + c + 1) * 64 + d];
    z1 += Z1[hh * 65 + c + 1];
    a2 += S2[(hh * 65 + c) * 64 + d];
    z2 += Z2[hh * 65 + c];
    const float E1 = fexp(s), E2 = fexp(0.2f * s);
    const float iz = 1.f / (E1 * z1 + E2 * z2);
    __builtin_nontemporal_store((E1 * a1 + E2 * a2) * iz, &out[i * 256 + t]);
    if (d == 0) {
        thrE[i * 4 + hh] = fexp(thr);
        A1[i * 4 + hh]   = E1 * iz;
        A2[i * 4 + hh]   = E2 * iz;
    }
}

// ---- K6: attn writer — 16384 blocks, quarter-row each, nontemporal ----
__global__ void k_attn(const f32x4* __restrict__ E1j4, const f32x4* __restrict__ E2j4,
                       const f32x4* __restrict__ thrE4, const f32x4* __restrict__ A14,
                       const f32x4* __restrict__ A24, f32x4* __restrict__ attn){
    const int bid = blockIdx.x;
    const int i = bid >> 2, qtr = bid & 3;
    const int t = threadIdx.x;
    const f32x4 th = thrE4[i];
    const f32x4 c1 = A14[i];
    const f32x4 c2 = A24[i];
    const f32x4* __restrict__ e1p = E1j4 + qtr * 1024;
    const f32x4* __restrict__ e2p = E2j4 + qtr * 1024;
    f32x4* __restrict__ row = attn + (size_t)i * NN + qtr * 1024;
    #pragma unroll
    for (int it = 0; it < 4; ++it) {
        const int j = it * 256 + t;
        const f32x4 e1 = e1p[j];
        const f32x4 e2 = e2p[j];
        f32x4 o;
        o.x = (e1.x >= th.x) ? c1.x * e1.x : c2.x * e2.x;
        o.y = (e1.y >= th.y) ? c1.y * e1.y : c2.y * e2.y;
        o.z = (e1.z >= th.z) ? c1.z * e1.z : c2.z * e2.z;
        o.w = (e1.w >= th.w) ? c1.w * e1.w : c2.w * e2.w;
        __builtin_nontemporal_store(o, &row[j]);
    }
}

extern "C" void kernel_launch(void* const* d_in, const int* in_sizes, int n_in,
                              void* d_out, int out_size, void* d_ws, size_t ws_size,
                              hipStream_t stream) {
    const float* h = (const float*)d_in[0];
    const float* W = (const float*)d_in[1];
    const float* a = (const float*)d_in[2];
    float* out = (float*)d_out;
    float* ws  = (float*)d_ws;

    float* Wh   = ws;                   // 1,048,576
    float* Whp  = Wh   + 1048576;       // 1,048,576
    float* fi   = Whp  + 1048576;       // 16,384
    float* fjT  = fi   + 16384;         // 16,384
    float* E1j  = fjT  + 16384;         // 16,384
    float* E2j  = E1j  + 16384;         // 16,384
    float* fs   = E2j  + 16384;         // 16,384
    float* cs1  = fs   + 16384;         // 16,384
    float* cs2  = cs1  + 16384;         // 16,384
    float* cz1  = cs2  + 16384;         // 256
    float* cz2  = cz1  + 256;           // 256
    float* S1   = cz2  + 256;           // 16,640
    float* S2   = S1   + 16640;         // 16,640
    float* Z1   = S2   + 16640;         // 260
    float* Z2   = Z1   + 260;           // 260
    float* thrE = Z2   + 260;           // 16,384
    float* A1   = thrE + 16384;         // 16,384
    float* A2   = A1   + 16384;         // 16,384

    k_gw    <<<NN / 8, 256, 0, stream>>>(h, W, a, Wh, fi, fjT, E1j, E2j);
    k_rp    <<<NN / 8, 256, 0, stream>>>(fjT, Wh, fs, Whp);
    k_chunks<<<64, 256, 0, stream>>>(fs, Whp, cs1, cs2, cz1, cz2);
    k_scan  <<<HEADS, 256, 0, stream>>>(cs1, cs2, cz1, cz2, S1, S2, Z1, Z2);
    k_q     <<<NN, 256, 0, stream>>>(fi, fs, Whp, S1, S2, Z1, Z2, out, thrE, A1, A2);

    float* attn = out + (NN * HEADS * OUT_DIM);
    k_attn  <<<NN * 4, 256, 0, stream>>>((const f32x4*)E1j, (const f32x4*)E2j,
                                         (const f32x4*)thrE, (const f32x4*)A1,
                                         (const f32x4*)A2, (f32x4*)attn);
}

// Round 8
// 133.443 us; speedup vs baseline: 1.2936x; 1.2936x over previous
//
#include <hip/hip_runtime.h>
#include <math.h>

#define NN 4096
#define IN_DIM 256
#define HEADS 4
#define OUT_DIM 64

typedef float f32x4 __attribute__((ext_vector_type(4)));

__device__ __forceinline__ float fexp(float x){ return __expf(x); }

// ---- K1: Wh = h@W fused with f tables. 256 blocks x 16 rows.
// Lane owns 4 cols, wave owns 4 rows: each ds_read_b128 feeds 16 FMAs (VALU-bound).
__global__ void k_gw(const float* __restrict__ h, const float* __restrict__ W,
                     const float* __restrict__ a,
                     float* __restrict__ Wh, float* __restrict__ fi, float* __restrict__ fjT,
                     float* __restrict__ E1j, float* __restrict__ E2j){
    __shared__ float4 hs4[16][64];        // 16 rows x 256 k (16 KB)
    const int i0 = blockIdx.x * 16;
    const int t  = threadIdx.x;
    const int w  = t >> 6, l = t & 63;    // wave, lane
    {
        const float4* h4 = (const float4*)h;
        hs4[w][l]      = h4[(i0 + w) * 64 + l];
        hs4[w + 4][l]  = h4[(i0 + w + 4) * 64 + l];
        hs4[w + 8][l]  = h4[(i0 + w + 8) * 64 + l];
        hs4[w + 12][l] = h4[(i0 + w + 12) * 64 + l];
    }
    __syncthreads();
    const int r0 = w * 4;                 // 4 rows per wave
    const float4* W4 = (const float4*)W;
    float4 acc[4];
    #pragma unroll
    for (int r = 0; r < 4; ++r) acc[r] = make_float4(0.f, 0.f, 0.f, 0.f);
    #pragma unroll 2
    for (int kq = 0; kq < 64; ++kq) {
        const float4 w0 = W4[(4 * kq + 0) * 64 + l];
        const float4 w1 = W4[(4 * kq + 1) * 64 + l];
        const float4 w2 = W4[(4 * kq + 2) * 64 + l];
        const float4 w3 = W4[(4 * kq + 3) * 64 + l];
        #pragma unroll
        for (int r = 0; r < 4; ++r) {
            const float4 hv = hs4[r0 + r][kq];   // wave-uniform LDS broadcast
            acc[r].x = fmaf(hv.x, w0.x, acc[r].x);
            acc[r].y = fmaf(hv.x, w0.y, acc[r].y);
            acc[r].z = fmaf(hv.x, w0.z, acc[r].z);
            acc[r].w = fmaf(hv.x, w0.w, acc[r].w);
            acc[r].x = fmaf(hv.y, w1.x, acc[r].x);
            acc[r].y = fmaf(hv.y, w1.y, acc[r].y);
            acc[r].z = fmaf(hv.y, w1.z, acc[r].z);
            acc[r].w = fmaf(hv.y, w1.w, acc[r].w);
            acc[r].x = fmaf(hv.z, w2.x, acc[r].x);
            acc[r].y = fmaf(hv.z, w2.y, acc[r].y);
            acc[r].z = fmaf(hv.z, w2.z, acc[r].z);
            acc[r].w = fmaf(hv.z, w2.w, acc[r].w);
            acc[r].x = fmaf(hv.w, w3.x, acc[r].x);
            acc[r].y = fmaf(hv.w, w3.y, acc[r].y);
            acc[r].z = fmaf(hv.w, w3.z, acc[r].z);
            acc[r].w = fmaf(hv.w, w3.w, acc[r].w);
        }
    }
    // epilogue: lane l covers cols l*4..l*4+3; head = l>>4; d = (l&15)*4+slot
    const int head = l >> 4;
    const int g = l & 15;                 // position within head's 16-lane group
    const float4 a4D = ((const float4*)a)[head * 32 + g];
    const float4 a4S = ((const float4*)a)[head * 32 + 16 + g];
    #pragma unroll
    for (int r = 0; r < 4; ++r) {
        const int n = i0 + r0 + r;
        ((float4*)Wh)[n * 64 + l] = acc[r];
        float p1 = acc[r].x * a4D.x + acc[r].y * a4D.y + acc[r].z * a4D.z + acc[r].w * a4D.w;
        float p2 = acc[r].x * a4S.x + acc[r].y * a4S.y + acc[r].z * a4S.z + acc[r].w * a4S.w;
        #pragma unroll
        for (int off = 8; off; off >>= 1) {
            p1 += __shfl_down(p1, off);
            p2 += __shfl_down(p2, off);
        }
        if (g == 0) {                     // leader lane of each head group
            fi[n * 4 + head]   = p1;
            fjT[head * NN + n] = p2;
            E1j[n * 4 + head]  = fexp(p2);
            E2j[n * 4 + head]  = fexp(0.2f * p2);
        }
    }
}

// ---- K2: rank f_j per head + permute Wh into sorted order ----
__global__ void k_rp(const float* __restrict__ fjT, const float* __restrict__ Wh,
                     float* __restrict__ fs, float* __restrict__ Whp){
    const int j0 = blockIdx.x * 8;
    const int t = threadIdx.x;
    const int hh = t >> 6, d = t & 63;    // wave == head
    const int base = hh * NN;
    float v[8]; int cnt[8];
    #pragma unroll
    for (int r = 0; r < 8; ++r) { v[r] = fjT[base + j0 + r]; cnt[r] = 0; }
    #pragma unroll 4
    for (int m = 0; m < 64; ++m) {
        const int jp = d + m * 64;
        const float x = fjT[base + jp];
        #pragma unroll
        for (int r = 0; r < 8; ++r)
            cnt[r] += (x < v[r] || (x == v[r] && jp < (j0 + r))) ? 1 : 0;
    }
    #pragma unroll
    for (int r = 0; r < 8; ++r) {
        int c = cnt[r];
        #pragma unroll
        for (int off = 32; off; off >>= 1) c += __shfl_down(c, off);
        const int rank = __shfl(c, 0);
        if (d == 0) fs[base + rank] = v[r];
        Whp[(size_t)(base + rank) * 64 + d] = Wh[(j0 + r) * 256 + hh * 64 + d];
    }
}

// ---- K3: per-chunk fine suffix/prefix sums + chunk totals ----
__global__ void k_chunks(const float* __restrict__ fs, const float* __restrict__ Whp,
                         float* __restrict__ r1, float* __restrict__ r2x,
                         float* __restrict__ rz1, float* __restrict__ rz2x,
                         float* __restrict__ cs1, float* __restrict__ cs2,
                         float* __restrict__ cz1, float* __restrict__ cz2){
    const int b = blockIdx.x;             // 4 heads * 64 chunks
    const int H = b >> 6, c = b & 63;
    const int t = threadIdx.x;            // 256 threads = 4 waves
    const int w = t >> 6, d = t & 63;
    const int base = H * NN;
    const int qw = c * 64 + w * 16;
    float wv[16], e1s[16], e2s[16];
    #pragma unroll
    for (int s = 0; s < 16; ++s) {
        const int q = qw + s;
        const float f = fs[base + q];
        e1s[s] = fexp(f);
        e2s[s] = fexp(0.2f * f);
        wv[s]  = Whp[(size_t)(base + q) * 64 + d];
    }
    float p2[16], s1[16], lz1[16], lz2[16];
    float acc2 = 0.f, z2 = 0.f;
    #pragma unroll
    for (int s = 0; s < 16; ++s) {
        p2[s] = acc2; lz2[s] = z2;
        acc2 += e2s[s] * wv[s]; z2 += e2s[s];
    }
    float acc1 = 0.f, z1 = 0.f;
    #pragma unroll
    for (int s = 15; s >= 0; --s) {
        acc1 += e1s[s] * wv[s]; z1 += e1s[s];
        s1[s] = acc1; lz1[s] = z1;
    }
    __shared__ float t1[4][64], t2[4][64], tz1[4], tz2[4];
    t1[w][d] = acc1; t2[w][d] = acc2;
    if (d == 0) { tz1[w] = z1; tz2[w] = z2; }
    __syncthreads();
    float off1 = 0.f, off2 = 0.f, zo1 = 0.f, zo2 = 0.f;
    #pragma unroll
    for (int w2 = 0; w2 < 4; ++w2) {
        if (w2 > w) { off1 += t1[w2][d]; zo1 += tz1[w2]; }
        if (w2 < w) { off2 += t2[w2][d]; zo2 += tz2[w2]; }
    }
    #pragma unroll
    for (int s = 0; s < 16; ++s) {
        const int q = qw + s;
        r1 [(size_t)(base + q) * 64 + d] = off1 + s1[s];
        r2x[(size_t)(base + q) * 64 + d] = off2 + p2[s];
        if (d == 0) {
            rz1 [base + q] = zo1 + lz1[s];
            rz2x[base + q] = zo2 + lz2[s];
        }
    }
    if (w == 0) {
        cs1[b * 64 + d] = off1 + acc1;
        if (d == 0) cz1[b] = zo1 + z1;
    }
    if (w == 3) {
        cs2[b * 64 + d] = off2 + acc2;
        if (d == 0) cz2[b] = zo2 + z2;
    }
}

// ---- K4: chunk-level scans (one block per head) ----
__global__ void k_scan(const float* __restrict__ cs1, const float* __restrict__ cs2,
                       const float* __restrict__ cz1, const float* __restrict__ cz2,
                       float* __restrict__ S1, float* __restrict__ S2,
                       float* __restrict__ Z1, float* __restrict__ Z2){
    const int H = blockIdx.x;
    const int t = threadIdx.x;
    if (t < 64) {
        const int d = t; float acc = 0.f;
        S1[(H * 65 + 64) * 64 + d] = 0.f;
        #pragma unroll 8
        for (int c = 63; c >= 0; --c) { acc += cs1[(H * 64 + c) * 64 + d]; S1[(H * 65 + c) * 64 + d] = acc; }
    } else if (t < 128) {
        const int d = t - 64; float acc = 0.f;
        S2[(H * 65 + 0) * 64 + d] = 0.f;
        #pragma unroll 8
        for (int c = 0; c < 64; ++c) { acc += cs2[(H * 64 + c) * 64 + d]; S2[(H * 65 + c + 1) * 64 + d] = acc; }
    } else if (t == 128) {
        float acc = 0.f; Z1[H * 65 + 64] = 0.f;
        for (int c = 63; c >= 0; --c) { acc += cz1[H * 64 + c]; Z1[H * 65 + c] = acc; }
    } else if (t == 129) {
        float acc = 0.f; Z2[H * 65 + 0] = 0.f;
        for (int c = 0; c < 64; ++c) { acc += cz2[H * 64 + c]; Z2[H * 65 + c + 1] = acc; }
    }
}

// ---- K5: fused query + attn row write (nontemporal stores) ----
__global__ void k_qa(const float* __restrict__ fi, const float* __restrict__ fs,
                     const float* __restrict__ r1, const float* __restrict__ r2x,
                     const float* __restrict__ rz1, const float* __restrict__ rz2x,
                     const float* __restrict__ S1, const float* __restrict__ S2,
                     const float* __restrict__ Z1, const float* __restrict__ Z2,
                     const f32x4* __restrict__ E1j4, const f32x4* __restrict__ E2j4,
                     float* __restrict__ out, f32x4* __restrict__ attn){
    const int i = blockIdx.x;
    const int t = threadIdx.x;
    const int hh = t >> 6, d = t & 63;    // wave == head
    const int base = hh * NN;
    __shared__ float sth[4], sa1[4], sa2[4];

    const float s = fi[i * 4 + hh];
    const float thr = -s;
    const unsigned long long m1 = __ballot(fs[base + d * 64] < thr);
    const int k1 = __popcll(m1);
    int p = 0;
    if (k1 > 0) {
        const int cc = k1 - 1;
        const unsigned long long m2 = __ballot(fs[base + cc * 64 + d] < thr);
        p = cc * 64 + __popcll(m2);
    }
    float a1, a2, z1, z2;
    if (p == NN) {
        a1 = 0.f; z1 = 0.f;
        a2 = S2[(hh * 65 + 64) * 64 + d]; z2 = Z2[hh * 65 + 64];
    } else {
        const int c = p >> 6;
        a1 = r1 [(size_t)(base + p) * 64 + d] + S1[(hh * 65 + c + 1) * 64 + d];
        z1 = rz1[base + p]                    + Z1[hh * 65 + c + 1];
        a2 = r2x[(size_t)(base + p) * 64 + d] + S2[(hh * 65 + c) * 64 + d];
        z2 = rz2x[base + p]                   + Z2[hh * 65 + c];
    }
    const float E1 = fexp(s), E2 = fexp(0.2f * s);
    const float iz = 1.f / (E1 * z1 + E2 * z2);
    __builtin_nontemporal_store((E1 * a1 + E2 * a2) * iz, &out[i * 256 + t]);
    if (d == 0) {
        sth[hh] = fexp(thr);
        sa1[hh] = E1 * iz;
        sa2[hh] = E2 * iz;
    }
    __syncthreads();
    const float th0 = sth[0], th1 = sth[1], th2 = sth[2], th3 = sth[3];
    const float c10 = sa1[0], c11 = sa1[1], c12 = sa1[2], c13 = sa1[3];
    const float c20 = sa2[0], c21 = sa2[1], c22 = sa2[2], c23 = sa2[3];
    f32x4* __restrict__ row = attn + (size_t)i * NN;
    #pragma unroll
    for (int it = 0; it < 16; ++it) {
        const int j = it * 256 + t;
        const f32x4 e1 = E1j4[j];
        const f32x4 e2 = E2j4[j];
        f32x4 o;
        o.x = (e1.x >= th0) ? c10 * e1.x : c20 * e2.x;
        o.y = (e1.y >= th1) ? c11 * e1.y : c21 * e2.y;
        o.z = (e1.z >= th2) ? c12 * e1.z : c22 * e2.z;
        o.w = (e1.w >= th3) ? c13 * e1.w : c23 * e2.w;
        __builtin_nontemporal_store(o, &row[j]);
    }
}

extern "C" void kernel_launch(void* const* d_in, const int* in_sizes, int n_in,
                              void* d_out, int out_size, void* d_ws, size_t ws_size,
                              hipStream_t stream) {
    const float* h = (const float*)d_in[0];
    const float* W = (const float*)d_in[1];
    const float* a = (const float*)d_in[2];
    float* out = (float*)d_out;
    float* ws  = (float*)d_ws;

    float* Wh   = ws;                   // 1,048,576
    float* Whp  = Wh   + 1048576;       // 1,048,576
    float* fi   = Whp  + 1048576;       // 16,384
    float* fjT  = fi   + 16384;         // 16,384
    float* E1j  = fjT  + 16384;         // 16,384
    float* E2j  = E1j  + 16384;         // 16,384
    float* fs   = E2j  + 16384;         // 16,384
    float* cs1  = fs   + 16384;         // 16,384
    float* cs2  = cs1  + 16384;         // 16,384
    float* cz1  = cs2  + 16384;         // 256
    float* cz2  = cz1  + 256;           // 256
    float* S1   = cz2  + 256;           // 16,640
    float* S2   = S1   + 16640;         // 16,640
    float* Z1   = S2   + 16640;         // 260
    float* Z2   = Z1   + 260;           // 260
    float* r1   = Z2   + 260;           // 1,048,576
    float* r2x  = r1   + 1048576;       // 1,048,576
    float* rz1  = r2x  + 1048576;       // 16,384
    float* rz2x = rz1  + 16384;         // 16,384

    k_gw    <<<NN / 16, 256, 0, stream>>>(h, W, a, Wh, fi, fjT, E1j, E2j);
    k_rp    <<<NN / 8, 256, 0, stream>>>(fjT, Wh, fs, Whp);
    k_chunks<<<HEADS * 64, 256, 0, stream>>>(fs, Whp, r1, r2x, rz1, rz2x, cs1, cs2, cz1, cz2);
    k_scan  <<<HEADS, 256, 0, stream>>>(cs1, cs2, cz1, cz2, S1, S2, Z1, Z2);

    float* attn = out + (NN * HEADS * OUT_DIM);
    k_qa    <<<NN, 256, 0, stream>>>(fi, fs, r1, r2x, rz1, rz2x, S1, S2, Z1, Z2,
                                     (const f32x4*)E1j, (const f32x4*)E2j,
                                     out, (f32x4*)attn);
}